// Round 9
// baseline (450.474 us; speedup 1.0000x reference)
//
#include <hip/hip_runtime.h>
#include <math.h>

#define NROWS 16384   // B*T
#define QROWS 4096
#define INCH  512
#define CH    2048
#define DD    256
#define MM    1024

typedef unsigned short u16;
typedef short short8 __attribute__((ext_vector_type(8)));
typedef float f32x4 __attribute__((ext_vector_type(4)));

__device__ __forceinline__ u16 f2bf(float f) {
  unsigned u = __float_as_uint(f);
  return (u16)((u + 0x7fffu + ((u >> 16) & 1u)) >> 16);
}
__device__ __forceinline__ float bf2f(u16 h) {
  return __uint_as_float(((unsigned)h) << 16);
}
__device__ __forceinline__ void gload16(const u16* g, u16* lds) {
  __builtin_amdgcn_global_load_lds((const __attribute__((address_space(1))) void*)g,
                                   (__attribute__((address_space(3))) void*)lds, 16, 0, 0);
}

// Coalesced-staging chunk mapping (16B chunks of 8 bf16 along K):
//   PC(row,kc) = (row>>4)*64 + (row&15)*4 + (kc ^ ((row>>1)&3))
//   frag read: chunk = group*64 + rI, rI = (lane&15)*4 + ((lane>>4)^((lane>>1)&3))

// ---------------------------------------------------------------------------
// split: fp32 -> bf16 hi/lo pair (quarter: 4096x512)
// ---------------------------------------------------------------------------
__global__ __launch_bounds__(256) void k_split_x(const float* __restrict__ x,
                                                 u16* __restrict__ xh, u16* __restrict__ xl) {
  const size_t i = ((size_t)blockIdx.x * 256 + threadIdx.x) * 8;
  float4 a = *(const float4*)(x + i);
  float4 b = *(const float4*)(x + i + 4);
  float v[8] = {a.x, a.y, a.z, a.w, b.x, b.y, b.z, b.w};
  unsigned hw[4], lw[4];
#pragma unroll
  for (int p = 0; p < 4; ++p) {
    u16 h0 = f2bf(v[2*p]), h1 = f2bf(v[2*p+1]);
    u16 l0 = f2bf(v[2*p] - bf2f(h0)), l1 = f2bf(v[2*p+1] - bf2f(h1));
    hw[p] = (unsigned)h0 | ((unsigned)h1 << 16);
    lw[p] = (unsigned)l0 | ((unsigned)l1 << 16);
  }
  *(uint4*)(xh + i) = make_uint4(hw[0], hw[1], hw[2], hw[3]);
  *(uint4*)(xl + i) = make_uint4(lw[0], lw[1], lw[2], lw[3]);
}

// src [R][C] fp32  ->  dh/dl [C][R] bf16 hi/lo   (transpose + split)
__global__ __launch_bounds__(256) void k_split_wT(const float* __restrict__ src,
                                                  u16* __restrict__ dh, u16* __restrict__ dl,
                                                  int R, int C) {
  __shared__ float t[32][33];
  const int tx = threadIdx.x & 31, ty = threadIdx.x >> 5;
  const int c0 = blockIdx.x * 32, r0 = blockIdx.y * 32;
#pragma unroll
  for (int i = 0; i < 4; ++i)
    t[ty + i * 8][tx] = src[(size_t)(r0 + ty + i * 8) * C + c0 + tx];
  __syncthreads();
#pragma unroll
  for (int i = 0; i < 4; ++i) {
    float v = t[tx][ty + i * 8];
    size_t o = (size_t)(c0 + ty + i * 8) * R + r0 + tx;
    u16 h = f2bf(v);
    dh[o] = h;
    dl[o] = f2bf(v - bf2f(h));
  }
}

// ---------------------------------------------------------------------------
// K1: H(split) = X @ W1. 128x128 tile, BK=32, 4 waves, coalesced staging,
// LDS-staged coalesced epilogue + per-slice row stats (sum h, sum h^2).
// ---------------------------------------------------------------------------
__global__ __launch_bounds__(256) void k_gemm1(const u16* __restrict__ Xh, const u16* __restrict__ Xl,
                                               const u16* __restrict__ W1ht, const u16* __restrict__ W1lt,
                                               u16* __restrict__ Hh, u16* __restrict__ Hl,
                                               float* __restrict__ STATS) {
  __shared__ u16 sm[2][2112 * 8];   // loop: 2048 chunks/buf; epilogue fp32 [128][132]
  const int tid = threadIdx.x;
  const int lane = tid & 63, w = tid >> 6;
  const int wr = w >> 1, wc = w & 1;
  const int gm = blockIdx.y * 128, n0 = blockIdx.x * 128;

  const u16* srcbase = (w == 0) ? Xh : (w == 1) ? Xl : (w == 2) ? W1ht : W1lt;
  const int rowbase = (w < 2) ? gm : n0;
  const int st_row = lane >> 2;
  const int st_k16 = (lane & 3) ^ ((lane >> 3) & 3);

  f32x4 acc[4][4];
#pragma unroll
  for (int i = 0; i < 4; ++i)
#pragma unroll
    for (int j = 0; j < 4; ++j) acc[i][j] = (f32x4){0.f, 0.f, 0.f, 0.f};

  auto STAGE = [&](int buf, int kt) {
#pragma unroll
    for (int t = 0; t < 8; ++t) {
      const int row = rowbase + t * 16 + st_row;
      const u16* g = srcbase + ((size_t)row << 9) + (kt << 5) + st_k16 * 8;
      gload16(g, &sm[buf][(w * 512 + t * 64 + lane) * 8]);
    }
  };

  STAGE(0, 0);
  const int rI = (lane & 15) * 4 + ((lane >> 4) ^ ((lane >> 1) & 3));
  for (int kt = 0; kt < 16; ++kt) {
    __syncthreads();
    if (kt + 1 < 16) STAGE((kt + 1) & 1, kt + 1);
    const u16* base = sm[kt & 1];
    short8 ah[4], al[4], bh[4], bl[4];
#pragma unroll
    for (int i = 0; i < 4; ++i) {
      ah[i] = *(const short8*)(base + ((wr * 4 + i) * 64 + rI) * 8);
      al[i] = *(const short8*)(base + (512 + (wr * 4 + i) * 64 + rI) * 8);
      bh[i] = *(const short8*)(base + (1024 + (wc * 4 + i) * 64 + rI) * 8);
      bl[i] = *(const short8*)(base + (1536 + (wc * 4 + i) * 64 + rI) * 8);
    }
#pragma unroll
    for (int i = 0; i < 4; ++i)
#pragma unroll
      for (int j = 0; j < 4; ++j) {
        acc[i][j] = __builtin_amdgcn_mfma_f32_16x16x32_bf16(ah[i], bh[j], acc[i][j], 0, 0, 0);
        acc[i][j] = __builtin_amdgcn_mfma_f32_16x16x32_bf16(ah[i], bl[j], acc[i][j], 0, 0, 0);
        acc[i][j] = __builtin_amdgcn_mfma_f32_16x16x32_bf16(al[i], bh[j], acc[i][j], 0, 0, 0);
      }
  }

  // ---- LDS-staged coalesced epilogue + row-stat partials ----
  __syncthreads();
  float* smf = (float*)&sm[0][0];           // view: [128][132] fp32
  const int rr = (lane >> 4) << 2, cc = lane & 15;
#pragma unroll
  for (int i = 0; i < 4; ++i)
#pragma unroll
    for (int j = 0; j < 4; ++j)
#pragma unroll
      for (int reg = 0; reg < 4; ++reg)
        smf[(wr * 64 + i * 16 + rr + reg) * 132 + (wc * 64 + j * 16 + cc)] = acc[i][j][reg];
  __syncthreads();
  const int trow = tid >> 4, tcg = tid & 15;
#pragma unroll
  for (int rr2 = 0; rr2 < 8; ++rr2) {
    const int r = rr2 * 16 + trow;
    float v[8];
    *(f32x4*)&v[0] = *(const f32x4*)&smf[r * 132 + tcg * 8];
    *(f32x4*)&v[4] = *(const f32x4*)&smf[r * 132 + tcg * 8 + 4];
    float s = 0.f, ss = 0.f;
#pragma unroll
    for (int e = 0; e < 8; ++e) { s += v[e]; ss += v[e] * v[e]; }
#pragma unroll
    for (int m = 1; m <= 8; m <<= 1) { s += __shfl_xor(s, m); ss += __shfl_xor(ss, m); }
    if (tcg == 0)
      *(float2*)&STATS[((size_t)(gm + r) << 5) + blockIdx.x * 2] = make_float2(s, ss);
    unsigned hw[4], lw[4];
#pragma unroll
    for (int p = 0; p < 4; ++p) {
      u16 h0 = f2bf(v[2*p]), h1 = f2bf(v[2*p+1]);
      u16 l0 = f2bf(v[2*p] - bf2f(h0)), l1 = f2bf(v[2*p+1] - bf2f(h1));
      hw[p] = (unsigned)h0 | ((unsigned)h1 << 16);
      lw[p] = (unsigned)l0 | ((unsigned)l1 << 16);
    }
    const size_t o = (size_t)(gm + r) * CH + n0 + tcg * 8;
    *(uint4*)&Hh[o] = make_uint4(hw[0], hw[1], hw[2], hw[3]);
    *(uint4*)&Hl[o] = make_uint4(lw[0], lw[1], lw[2], lw[3]);
  }
}

// ---------------------------------------------------------------------------
// K2: reduce 16 slice-partials per row -> (mu, rinv)
// ---------------------------------------------------------------------------
__global__ __launch_bounds__(256) void k_rowstats(const float* __restrict__ STATS,
                                                  float2* __restrict__ MU2) {
  const int row = blockIdx.x * 256 + threadIdx.x;
  float s = 0.f, ss = 0.f;
#pragma unroll
  for (int i = 0; i < 16; ++i) {
    float2 p = *(const float2*)&STATS[((size_t)row << 5) + i * 2];
    s += p.x; ss += p.y;
  }
  const float mu = s * (1.f / CH);
  const float var = ss * (1.f / CH) - mu * mu;
  MU2[row] = make_float2(mu, 1.f / sqrtf(var + 1e-5f));
}

// ---------------------------------------------------------------------------
// K3: fused Z = relu(LN(H)) @ W2 + b2 -> per-head LSE -> Z, EXh/EXl, SELF2.
// BM=64, BN=128 (2 heads/block), BK=32, 256 thr (4 waves 2x2), 48KB dbuf LDS
// -> 2 blocks/CU. A: global->reg->LN->split->ds_write (all threads);
// B: 4 gload16/thread. Chunks/buf: Ah[0,256) Al[256,512) Bh[512,1024) Bl[1024,1536)
// ---------------------------------------------------------------------------
__global__ __launch_bounds__(256) void k_gemm2(const u16* __restrict__ Hh, const u16* __restrict__ Hl,
                                               const u16* __restrict__ W2ht, const u16* __restrict__ W2lt,
                                               const float* __restrict__ lng, const float* __restrict__ lnb,
                                               const float2* __restrict__ MU2,
                                               const float* __restrict__ b2,
                                               float* __restrict__ Z,
                                               u16* __restrict__ EXh, u16* __restrict__ EXl,
                                               float* __restrict__ SELF2) {
  __shared__ u16 sm[2][1536 * 8];   // 48 KB
  __shared__ float selfp[64][2];
  const int tid = threadIdx.x;
  const int lane = tid & 63, w = tid >> 6;
  const int wr = w >> 1, wc = w & 1;
  const int gm = blockIdx.x * 64, n0 = blockIdx.y * 128;

  // A site: row arow (0..63), k16-chunk akc (0..3)
  const int arow = tid >> 2, akc = tid & 3;
  const int pcA = (arow >> 4) * 64 + (arow & 15) * 4 + (akc ^ ((arow >> 1) & 3));
  const float2 murv = MU2[gm + arow];
  const u16* gHh = Hh + ((size_t)(gm + arow) << 11) + akc * 8;
  const u16* gHl = Hl + ((size_t)(gm + arow) << 11) + akc * 8;

  f32x4 acc[2][4];
#pragma unroll
  for (int i = 0; i < 2; ++i)
#pragma unroll
    for (int j = 0; j < 4; ++j) acc[i][j] = (f32x4){0.f, 0.f, 0.f, 0.f};

  uint4 hwreg, lwreg;
  auto A_LOAD = [&](int kt) {
    hwreg = *(const uint4*)(gHh + kt * 32);
    lwreg = *(const uint4*)(gHl + kt * 32);
  };
  auto B_STAGE = [&](int buf, int kt) {
#pragma unroll
    for (int t = 0; t < 4; ++t) {
      const int f = t * 256 + tid;            // [0,1024)
      const int split = f >> 9;               // wave-uniform
      const int wi = f & 511;
      const int grp = wi >> 6;                // wave-uniform
      const int s = wi & 63;
      const int row = n0 + grp * 16 + (s >> 2);
      const int k16 = (s & 3) ^ ((s >> 3) & 3);
      const u16* src = split ? W2lt : W2ht;
      gload16(src + ((size_t)row << 11) + (kt << 5) + k16 * 8,
              &sm[buf][(size_t)(512 + f) * 8]);
    }
  };
  auto LN_WRITE = [&](int buf, int kt) {
    const int kb = kt * 32 + akc * 8;
    float4 g0 = *(const float4*)&lng[kb];
    float4 g1 = *(const float4*)&lng[kb + 4];
    float4 bb0 = *(const float4*)&lnb[kb];
    float4 bb1 = *(const float4*)&lnb[kb + 4];
    const float gg[8] = {g0.x, g0.y, g0.z, g0.w, g1.x, g1.y, g1.z, g1.w};
    const float bb[8] = {bb0.x, bb0.y, bb0.z, bb0.w, bb1.x, bb1.y, bb1.z, bb1.w};
    const unsigned hws[4] = {hwreg.x, hwreg.y, hwreg.z, hwreg.w};
    const unsigned lws[4] = {lwreg.x, lwreg.y, lwreg.z, lwreg.w};
    unsigned oh[4], ol[4];
#pragma unroll
    for (int p = 0; p < 4; ++p) {
      u16 yh[2], yl[2];
#pragma unroll
      for (int e = 0; e < 2; ++e) {
        const u16 hu = (u16)(hws[p] >> (16 * e));
        const u16 lu = (u16)(lws[p] >> (16 * e));
        const float h = bf2f(hu) + bf2f(lu);
        const float a1 = murv.y * gg[2 * p + e];
        const float y = fmaxf(fmaf(h, a1, bb[2 * p + e] - murv.x * a1), 0.f);
        yh[e] = f2bf(y);
        yl[e] = f2bf(y - bf2f(yh[e]));
      }
      oh[p] = (unsigned)yh[0] | ((unsigned)yh[1] << 16);
      ol[p] = (unsigned)yl[0] | ((unsigned)yl[1] << 16);
    }
    *(uint4*)&sm[buf][(size_t)pcA * 8] = make_uint4(oh[0], oh[1], oh[2], oh[3]);
    *(uint4*)&sm[buf][(size_t)(256 + pcA) * 8] = make_uint4(ol[0], ol[1], ol[2], ol[3]);
  };

  // prologue: fill buf 0
  A_LOAD(0);
  B_STAGE(0, 0);
  LN_WRITE(0, 0);

  const int lr = lane & 15;
  const int rI = lr * 4 + ((lane >> 4) ^ ((lr >> 1) & 3));
  for (int kt = 0; kt < 64; ++kt) {
    __syncthreads();                 // buf[kt&1] ready
    if (kt + 1 < 64) {
      A_LOAD(kt + 1);                // HBM latency hides under MFMA
      B_STAGE((kt + 1) & 1, kt + 1);
    }
    const u16* base = sm[kt & 1];
    short8 ah[2], al[2], bh[4], bl[4];
#pragma unroll
    for (int i = 0; i < 2; ++i) {
      ah[i] = *(const short8*)(base + ((wr * 2 + i) * 64 + rI) * 8);
      al[i] = *(const short8*)(base + (256 + (wr * 2 + i) * 64 + rI) * 8);
    }
#pragma unroll
    for (int j = 0; j < 4; ++j) {
      bh[j] = *(const short8*)(base + (512 + (wc * 4 + j) * 64 + rI) * 8);
      bl[j] = *(const short8*)(base + (1024 + (wc * 4 + j) * 64 + rI) * 8);
    }
#pragma unroll
    for (int i = 0; i < 2; ++i)
#pragma unroll
      for (int j = 0; j < 4; ++j) {
        acc[i][j] = __builtin_amdgcn_mfma_f32_16x16x32_bf16(ah[i], bh[j], acc[i][j], 0, 0, 0);
        acc[i][j] = __builtin_amdgcn_mfma_f32_16x16x32_bf16(ah[i], bl[j], acc[i][j], 0, 0, 0);
        acc[i][j] = __builtin_amdgcn_mfma_f32_16x16x32_bf16(al[i], bh[j], acc[i][j], 0, 0, 0);
      }
    if (kt + 1 < 64) LN_WRITE((kt + 1) & 1, kt + 1);
  }

  // fused epilogue: bias + per-head (64-col == wave's wc) LSE
  const int cc = lane & 15;
  float bias[4];
#pragma unroll
  for (int j = 0; j < 4; ++j) bias[j] = b2[n0 + wc * 64 + j * 16 + cc];

#pragma unroll
  for (int i = 0; i < 2; ++i)
#pragma unroll
    for (int reg = 0; reg < 4; ++reg) {
      const int rl = wr * 32 + i * 16 + ((lane >> 4) << 2) + reg;   // row in [0,64)
      const int row = gm + rl;
      float z[4];
#pragma unroll
      for (int j = 0; j < 4; ++j) z[j] = acc[i][j][reg] + bias[j];
      float mx = fmaxf(fmaxf(z[0], z[1]), fmaxf(z[2], z[3]));
#pragma unroll
      for (int m = 1; m <= 8; m <<= 1) mx = fmaxf(mx, __shfl_xor(mx, m));
      float se = expf(z[0] - mx) + expf(z[1] - mx) + expf(z[2] - mx) + expf(z[3] - mx);
#pragma unroll
      for (int m = 1; m <= 8; m <<= 1) se += __shfl_xor(se, m);
      const float lse = mx + logf(se);
      float selfc = 0.f;
#pragma unroll
      for (int j = 0; j < 4; ++j) {
        const float p = z[j] - lse;
        const float e = expf(p);
        selfc += e * p;
        const size_t o = (size_t)row * DD + n0 + wc * 64 + j * 16 + cc;
        Z[o] = z[j];
        u16 h = f2bf(e);
        EXh[o] = h;
        EXl[o] = f2bf(e - bf2f(h));
      }
#pragma unroll
      for (int m = 1; m <= 8; m <<= 1) selfc += __shfl_xor(selfc, m);
      if (cc == 0) {
        if (wc == 0) selfp[rl][0] = selfc;
        else         selfp[rl][1] = selfc;
      }
    }
  __syncthreads();
  if (tid < 64)
    SELF2[(size_t)(gm + tid) * 2 + blockIdx.y] = selfp[tid][0] + selfp[tid][1];
}

// ---------------------------------------------------------------------------
// K4: logE = log(emb), 3-split bf16 (hi/mid/lo), layout [1024][256]
// ---------------------------------------------------------------------------
__global__ __launch_bounds__(256) void k_prep_le(const float* __restrict__ E,
                                                 u16* __restrict__ LEh, u16* __restrict__ LEm,
                                                 u16* __restrict__ LEl) {
  const size_t i = ((size_t)blockIdx.x * 256 + threadIdx.x) * 4;
  float4 v4 = *(const float4*)&E[i];
  float v[4] = {logf(v4.x), logf(v4.y), logf(v4.z), logf(v4.w)};
  u16 h[4], m_[4], l[4];
#pragma unroll
  for (int e = 0; e < 4; ++e) {
    h[e] = f2bf(v[e]);
    float r1 = v[e] - bf2f(h[e]);
    m_[e] = f2bf(r1);
    float r2 = r1 - bf2f(m_[e]);
    l[e] = f2bf(r2);
  }
  *(uint2*)&LEh[i] = make_uint2((unsigned)h[0] | ((unsigned)h[1] << 16), (unsigned)h[2] | ((unsigned)h[3] << 16));
  *(uint2*)&LEm[i] = make_uint2((unsigned)m_[0] | ((unsigned)m_[1] << 16), (unsigned)m_[2] | ((unsigned)m_[3] << 16));
  *(uint2*)&LEl[i] = make_uint2((unsigned)l[0] | ((unsigned)l[1] << 16), (unsigned)l[2] | ((unsigned)l[3] << 16));
}

// ---------------------------------------------------------------------------
// K5: dots = EX @ LE^T (5-term split MFMA), tile 128x64, DOUBLE-BUFFERED,
// fused per-32-col argmax -> PV/PI [N][32]. 4 waves 2x2 (wave 64r x 32c).
// Chunks/buf (1792): EXh[0,512) EXl[512,1024) LEh[1024,1280) LEm[1280,1536) LEl[1536,1792)
// ---------------------------------------------------------------------------
__global__ __launch_bounds__(256) void k_dots(const u16* __restrict__ EXh, const u16* __restrict__ EXl,
                                              const u16* __restrict__ LEh, const u16* __restrict__ LEm,
                                              const u16* __restrict__ LEl,
                                              float* __restrict__ PV, int* __restrict__ PI) {
  __shared__ u16 sm[2][1792 * 8];   // 56 KB
  const int tid = threadIdx.x;
  const int lane = tid & 63, w = tid >> 6;
  const int wr = w >> 1, wc = w & 1;
  const int gm = blockIdx.y * 128, m0 = blockIdx.x * 64;

  f32x4 acc[4][2];
#pragma unroll
  for (int i = 0; i < 4; ++i)
#pragma unroll
    for (int j = 0; j < 2; ++j) acc[i][j] = (f32x4){0.f, 0.f, 0.f, 0.f};

  auto STAGE = [&](int buf, int kt) {
#pragma unroll
    for (int t = 0; t < 7; ++t) {
      const int f = t * 256 + tid;            // [0,1792)
      const u16* src;
      int rowbase, grp, s;
      if (f < 1024) {
        const int split = f >> 9;             // wave-uniform
        const int wi = f & 511;
        grp = wi >> 6; s = wi & 63;
        src = split ? EXl : EXh;
        rowbase = gm;
      } else {
        const int fb = f - 1024;
        const int lsp = fb >> 8;              // wave-uniform
        const int wi = fb & 255;
        grp = wi >> 6; s = wi & 63;
        src = (lsp == 0) ? LEh : (lsp == 1) ? LEm : LEl;
        rowbase = m0;
      }
      const int row = rowbase + grp * 16 + (s >> 2);
      const int k16 = (s & 3) ^ ((s >> 3) & 3);
      gload16(src + ((size_t)row << 8) + (kt << 5) + k16 * 8,
              &sm[buf][(size_t)f * 8]);
    }
  };

  STAGE(0, 0);
  const int rI = (lane & 15) * 4 + ((lane >> 4) ^ ((lane >> 1) & 3));
  for (int kt = 0; kt < 8; ++kt) {
    __syncthreads();
    if (kt + 1 < 8) STAGE((kt + 1) & 1, kt + 1);
    const u16* base = sm[kt & 1];
    short8 eh[4], el[4], bh[2], bm[2], bl[2];
#pragma unroll
    for (int i = 0; i < 4; ++i) {
      eh[i] = *(const short8*)(base + ((wr * 4 + i) * 64 + rI) * 8);
      el[i] = *(const short8*)(base + (512 + (wr * 4 + i) * 64 + rI) * 8);
    }
#pragma unroll
    for (int j = 0; j < 2; ++j) {
      bh[j] = *(const short8*)(base + (1024 + (wc * 2 + j) * 64 + rI) * 8);
      bm[j] = *(const short8*)(base + (1280 + (wc * 2 + j) * 64 + rI) * 8);
      bl[j] = *(const short8*)(base + (1536 + (wc * 2 + j) * 64 + rI) * 8);
    }
#pragma unroll
    for (int i = 0; i < 4; ++i)
#pragma unroll
      for (int j = 0; j < 2; ++j) {
        acc[i][j] = __builtin_amdgcn_mfma_f32_16x16x32_bf16(eh[i], bh[j], acc[i][j], 0, 0, 0);
        acc[i][j] = __builtin_amdgcn_mfma_f32_16x16x32_bf16(eh[i], bm[j], acc[i][j], 0, 0, 0);
        acc[i][j] = __builtin_amdgcn_mfma_f32_16x16x32_bf16(eh[i], bl[j], acc[i][j], 0, 0, 0);
        acc[i][j] = __builtin_amdgcn_mfma_f32_16x16x32_bf16(el[i], bh[j], acc[i][j], 0, 0, 0);
        acc[i][j] = __builtin_amdgcn_mfma_f32_16x16x32_bf16(el[i], bm[j], acc[i][j], 0, 0, 0);
      }
  }

  // fused per-row argmax over this wave's 32 cols (tie-break: min global idx)
  const int cc = lane & 15;
  const int mtile = blockIdx.x * 2 + wc;              // [0,32)
#pragma unroll
  for (int i = 0; i < 4; ++i)
#pragma unroll
    for (int reg = 0; reg < 4; ++reg) {
      float bv = acc[i][0][reg];
      int bi = m0 + wc * 32 + cc;
      {
        const float v = acc[i][1][reg];
        if (v > bv) { bv = v; bi = m0 + wc * 32 + 16 + cc; }
      }
#pragma unroll
      for (int msk = 8; msk; msk >>= 1) {
        const float ov = __shfl_xor(bv, msk);
        const int   oi = __shfl_xor(bi, msk);
        if (ov > bv || (ov == bv && oi < bi)) { bv = ov; bi = oi; }
      }
      if (cc == 0) {
        const int row = gm + wr * 64 + i * 16 + ((lane >> 4) << 2) + reg;
        PV[row * 32 + mtile] = bv;
        PI[row * 32 + mtile] = bi;
      }
    }
}

// ---------------------------------------------------------------------------
// K6: per row: reduce 32 partials, KL = self - best, gather Q. Wave per row.
// ---------------------------------------------------------------------------
__global__ __launch_bounds__(256) void k_scan(const float* __restrict__ PV,
                                              const int* __restrict__ PI,
                                              const float* __restrict__ SELF2,
                                              const float* __restrict__ E,
                                              float* __restrict__ Q,
                                              float* __restrict__ KL) {
  const int tid = threadIdx.x;
  const int lane = tid & 63;
  const int row = blockIdx.x * 4 + (tid >> 6);

  float bv = -1e30f;
  int bi = 0x7fffffff;
  if (lane < 32) { bv = PV[row * 32 + lane]; bi = PI[row * 32 + lane]; }
#pragma unroll
  for (int m = 32; m; m >>= 1) {
    const float ov = __shfl_xor(bv, m);
    const int   oi = __shfl_xor(bi, m);
    if (ov > bv || (ov == bv && oi < bi)) { bv = ov; bi = oi; }
  }
  if (lane == 0) KL[row] = SELF2[(size_t)row * 2] + SELF2[(size_t)row * 2 + 1] - bv;
  float4 e4 = *(const float4*)&E[((size_t)bi << 8) + lane * 4];
  *(float4*)&Q[((size_t)row << 8) + lane * 4] = e4;
}

// ---------------------------------------------------------------------------
// K7: loss = 0.25/B * sum_n kl[n]*mask[n]
// ---------------------------------------------------------------------------
__global__ __launch_bounds__(256) void k_loss(const float* __restrict__ KL,
                                              const float* __restrict__ MASK,
                                              float* __restrict__ out) {
  __shared__ float red[4];
  const int tid = threadIdx.x;
  float s = 0.f;
  for (int i = tid; i < NROWS; i += 256) s += KL[i] * MASK[i];
#pragma unroll
  for (int m = 32; m; m >>= 1) s += __shfl_xor(s, m);
  if ((tid & 63) == 0) red[tid >> 6] = s;
  __syncthreads();
  if (tid == 0) out[0] = (red[0] + red[1] + red[2] + red[3]) * (0.25f / 16.f);
}

// ---------------------------------------------------------------------------
extern "C" void kernel_launch(void* const* d_in, const int* in_sizes, int n_in,
                              void* d_out, int out_size, void* d_ws, size_t ws_size,
                              hipStream_t stream) {
  const float* x     = (const float*)d_in[0];
  const float* masks = (const float*)d_in[1];
  const float* W1    = (const float*)d_in[2];
  const float* ln_g  = (const float*)d_in[3];
  const float* ln_b  = (const float*)d_in[4];
  const float* W2    = (const float*)d_in[5];
  const float* b2    = (const float*)d_in[6];
  const float* emb   = (const float*)d_in[7];

  float* z_out = (float*)d_out;
  float* q_out = z_out + (size_t)NROWS * DD;
  float* loss_out = z_out + 2 * (size_t)NROWS * DD;

  char* ws = (char*)d_ws;
  u16*   Hh    = (u16*)(ws);                   //  67,108,864 (16384x2048)
  u16*   Hl    = (u16*)(ws + 67108864);        //  67,108,864
  u16*   W1ht  = (u16*)(ws + 134217728);       //   2,097,152
  u16*   W1lt  = (u16*)(ws + 136314880);       //   2,097,152
  u16*   W2ht  = (u16*)(ws + 138412032);       //   1,048,576
  u16*   W2lt  = (u16*)(ws + 139460608);       //   1,048,576
  u16*   LEh   = (u16*)(ws + 140509184);       //     524,288
  u16*   LEm   = (u16*)(ws + 141033472);       //     524,288
  u16*   LEl   = (u16*)(ws + 141557760);       //     524,288
  float* SELF2 = (float*)(ws + 142082048);     //     131,072
  float* KL    = (float*)(ws + 142213120);     //      65,536
  u16*   Xh    = (u16*)(ws + 142278656);       //   4,194,304 (quarter 4096x512)
  u16*   Xl    = (u16*)(ws + 146472960);       //   4,194,304
  float2* MU2  = (float2*)(ws + 150667264);    //     131,072 -> end 150,798,336
  // overlays:
  float* PV    = (float*)(ws);                 //   2 MB (over Hh; H dead after gemm2)
  int*   PI    = (int*)(ws + 2097152);         //   2 MB
  float* STATS = (float*)q_out;                //   2 MB (q_out; dead before EX written)
  u16*   EXh   = (u16*)q_out;                  //   8 MB (after STATS consumed)
  u16*   EXl   = EXh + (size_t)NROWS * DD;     //   8 MB

  k_split_wT<<<dim3(64, 16), 256, 0, stream>>>(W1, W1ht, W1lt, INCH, CH);
  k_split_wT<<<dim3(8, 64), 256, 0, stream>>>(W2, W2ht, W2lt, CH, DD);
  k_prep_le<<<256, 256, 0, stream>>>(emb, LEh, LEm, LEl);

  for (int q = 0; q < 4; ++q) {
    const size_t xo = (size_t)q * QROWS * INCH;
    const size_t ho = (size_t)q * QROWS * CH;
    k_split_x<<<1024, 256, 0, stream>>>(x + xo, Xh, Xl);
    k_gemm1<<<dim3(16, 32), 256, 0, stream>>>(Xh, Xl, W1ht, W1lt, Hh + ho, Hl + ho,
                                              STATS + (size_t)q * QROWS * 32);
  }
  k_rowstats<<<NROWS / 256, 256, 0, stream>>>(STATS, MU2);
  k_gemm2<<<dim3(NROWS / 64, 2), 256, 0, stream>>>(Hh, Hl, W2ht, W2lt, ln_g, ln_b, MU2, b2,
                                                   z_out, EXh, EXl, SELF2);

  k_dots<<<dim3(16, 128), 256, 0, stream>>>(EXh, EXl, LEh, LEm, LEl, PV, PI);
  k_scan<<<4096, 256, 0, stream>>>(PV, PI, SELF2, emb, q_out, KL);
  k_loss<<<1, 256, 0, stream>>>(KL, masks, loss_out);
}

// Round 10
// 362.788 us; speedup vs baseline: 1.2417x; 1.2417x over previous
//
#include <hip/hip_runtime.h>
#include <math.h>

#define NROWS 16384   // B*T
#define QROWS 4096
#define INCH  512
#define CH    2048
#define DD    256
#define MM    1024

typedef unsigned short u16;
typedef short short8 __attribute__((ext_vector_type(8)));
typedef float f32x4 __attribute__((ext_vector_type(4)));

__device__ __forceinline__ u16 f2bf(float f) {
  unsigned u = __float_as_uint(f);
  return (u16)((u + 0x7fffu + ((u >> 16) & 1u)) >> 16);
}
__device__ __forceinline__ float bf2f(u16 h) {
  return __uint_as_float(((unsigned)h) << 16);
}
__device__ __forceinline__ void gload16(const u16* g, u16* lds) {
  __builtin_amdgcn_global_load_lds((const __attribute__((address_space(1))) void*)g,
                                   (__attribute__((address_space(3))) void*)lds, 16, 0, 0);
}

// Coalesced-staging chunk mapping (16B chunks of 8 bf16 along K):
//   PC(row,kc) = (row>>4)*64 + (row&15)*4 + (kc ^ ((row>>1)&3))
//   frag read: chunk = group*64 + rI, rI = (lane&15)*4 + ((lane>>4)^((lane>>1)&3))

// ---------------------------------------------------------------------------
// split: fp32 -> bf16 hi/lo pair (quarter: 4096x512)
// ---------------------------------------------------------------------------
__global__ __launch_bounds__(256) void k_split_x(const float* __restrict__ x,
                                                 u16* __restrict__ xh, u16* __restrict__ xl) {
  const size_t i = ((size_t)blockIdx.x * 256 + threadIdx.x) * 8;
  float4 a = *(const float4*)(x + i);
  float4 b = *(const float4*)(x + i + 4);
  float v[8] = {a.x, a.y, a.z, a.w, b.x, b.y, b.z, b.w};
  unsigned hw[4], lw[4];
#pragma unroll
  for (int p = 0; p < 4; ++p) {
    u16 h0 = f2bf(v[2*p]), h1 = f2bf(v[2*p+1]);
    u16 l0 = f2bf(v[2*p] - bf2f(h0)), l1 = f2bf(v[2*p+1] - bf2f(h1));
    hw[p] = (unsigned)h0 | ((unsigned)h1 << 16);
    lw[p] = (unsigned)l0 | ((unsigned)l1 << 16);
  }
  *(uint4*)(xh + i) = make_uint4(hw[0], hw[1], hw[2], hw[3]);
  *(uint4*)(xl + i) = make_uint4(lw[0], lw[1], lw[2], lw[3]);
}

// src [R][C] fp32  ->  dh/dl [C][R] bf16 hi/lo   (transpose + split)
__global__ __launch_bounds__(256) void k_split_wT(const float* __restrict__ src,
                                                  u16* __restrict__ dh, u16* __restrict__ dl,
                                                  int R, int C) {
  __shared__ float t[32][33];
  const int tx = threadIdx.x & 31, ty = threadIdx.x >> 5;
  const int c0 = blockIdx.x * 32, r0 = blockIdx.y * 32;
#pragma unroll
  for (int i = 0; i < 4; ++i)
    t[ty + i * 8][tx] = src[(size_t)(r0 + ty + i * 8) * C + c0 + tx];
  __syncthreads();
#pragma unroll
  for (int i = 0; i < 4; ++i) {
    float v = t[tx][ty + i * 8];
    size_t o = (size_t)(c0 + ty + i * 8) * R + r0 + tx;
    u16 h = f2bf(v);
    dh[o] = h;
    dl[o] = f2bf(v - bf2f(h));
  }
}

// ---------------------------------------------------------------------------
// K1: H(split) = X @ W1. 128x128 tile, BK=32, 4 waves, coalesced staging,
// LDS-staged coalesced epilogue + per-slice row stats (sum h, sum h^2).
// ---------------------------------------------------------------------------
__global__ __launch_bounds__(256) void k_gemm1(const u16* __restrict__ Xh, const u16* __restrict__ Xl,
                                               const u16* __restrict__ W1ht, const u16* __restrict__ W1lt,
                                               u16* __restrict__ Hh, u16* __restrict__ Hl,
                                               float* __restrict__ STATS) {
  __shared__ u16 sm[2][2112 * 8];   // loop: 2048 chunks/buf; epilogue fp32 [128][132]
  const int tid = threadIdx.x;
  const int lane = tid & 63, w = tid >> 6;
  const int wr = w >> 1, wc = w & 1;
  const int gm = blockIdx.y * 128, n0 = blockIdx.x * 128;

  const u16* srcbase = (w == 0) ? Xh : (w == 1) ? Xl : (w == 2) ? W1ht : W1lt;
  const int rowbase = (w < 2) ? gm : n0;
  const int st_row = lane >> 2;
  const int st_k16 = (lane & 3) ^ ((lane >> 3) & 3);

  f32x4 acc[4][4];
#pragma unroll
  for (int i = 0; i < 4; ++i)
#pragma unroll
    for (int j = 0; j < 4; ++j) acc[i][j] = (f32x4){0.f, 0.f, 0.f, 0.f};

  auto STAGE = [&](int buf, int kt) {
#pragma unroll
    for (int t = 0; t < 8; ++t) {
      const int row = rowbase + t * 16 + st_row;
      const u16* g = srcbase + ((size_t)row << 9) + (kt << 5) + st_k16 * 8;
      gload16(g, &sm[buf][(w * 512 + t * 64 + lane) * 8]);
    }
  };

  STAGE(0, 0);
  const int rI = (lane & 15) * 4 + ((lane >> 4) ^ ((lane >> 1) & 3));
  for (int kt = 0; kt < 16; ++kt) {
    __syncthreads();
    if (kt + 1 < 16) STAGE((kt + 1) & 1, kt + 1);
    const u16* base = sm[kt & 1];
    short8 ah[4], al[4], bh[4], bl[4];
#pragma unroll
    for (int i = 0; i < 4; ++i) {
      ah[i] = *(const short8*)(base + ((wr * 4 + i) * 64 + rI) * 8);
      al[i] = *(const short8*)(base + (512 + (wr * 4 + i) * 64 + rI) * 8);
      bh[i] = *(const short8*)(base + (1024 + (wc * 4 + i) * 64 + rI) * 8);
      bl[i] = *(const short8*)(base + (1536 + (wc * 4 + i) * 64 + rI) * 8);
    }
#pragma unroll
    for (int i = 0; i < 4; ++i)
#pragma unroll
      for (int j = 0; j < 4; ++j) {
        acc[i][j] = __builtin_amdgcn_mfma_f32_16x16x32_bf16(ah[i], bh[j], acc[i][j], 0, 0, 0);
        acc[i][j] = __builtin_amdgcn_mfma_f32_16x16x32_bf16(ah[i], bl[j], acc[i][j], 0, 0, 0);
        acc[i][j] = __builtin_amdgcn_mfma_f32_16x16x32_bf16(al[i], bh[j], acc[i][j], 0, 0, 0);
      }
  }

  // ---- LDS-staged coalesced epilogue + row-stat partials ----
  __syncthreads();
  float* smf = (float*)&sm[0][0];           // view: [128][132] fp32
  const int rr = (lane >> 4) << 2, cc = lane & 15;
#pragma unroll
  for (int i = 0; i < 4; ++i)
#pragma unroll
    for (int j = 0; j < 4; ++j)
#pragma unroll
      for (int reg = 0; reg < 4; ++reg)
        smf[(wr * 64 + i * 16 + rr + reg) * 132 + (wc * 64 + j * 16 + cc)] = acc[i][j][reg];
  __syncthreads();
  const int trow = tid >> 4, tcg = tid & 15;
#pragma unroll
  for (int rr2 = 0; rr2 < 8; ++rr2) {
    const int r = rr2 * 16 + trow;
    float v[8];
    *(f32x4*)&v[0] = *(const f32x4*)&smf[r * 132 + tcg * 8];
    *(f32x4*)&v[4] = *(const f32x4*)&smf[r * 132 + tcg * 8 + 4];
    float s = 0.f, ss = 0.f;
#pragma unroll
    for (int e = 0; e < 8; ++e) { s += v[e]; ss += v[e] * v[e]; }
#pragma unroll
    for (int m = 1; m <= 8; m <<= 1) { s += __shfl_xor(s, m); ss += __shfl_xor(ss, m); }
    if (tcg == 0)
      *(float2*)&STATS[((size_t)(gm + r) << 5) + blockIdx.x * 2] = make_float2(s, ss);
    unsigned hw[4], lw[4];
#pragma unroll
    for (int p = 0; p < 4; ++p) {
      u16 h0 = f2bf(v[2*p]), h1 = f2bf(v[2*p+1]);
      u16 l0 = f2bf(v[2*p] - bf2f(h0)), l1 = f2bf(v[2*p+1] - bf2f(h1));
      hw[p] = (unsigned)h0 | ((unsigned)h1 << 16);
      lw[p] = (unsigned)l0 | ((unsigned)l1 << 16);
    }
    const size_t o = (size_t)(gm + r) * CH + n0 + tcg * 8;
    *(uint4*)&Hh[o] = make_uint4(hw[0], hw[1], hw[2], hw[3]);
    *(uint4*)&Hl[o] = make_uint4(lw[0], lw[1], lw[2], lw[3]);
  }
}

// ---------------------------------------------------------------------------
// K2: reduce 16 slice-partials per row -> (mu, rinv)
// ---------------------------------------------------------------------------
__global__ __launch_bounds__(256) void k_rowstats(const float* __restrict__ STATS,
                                                  float2* __restrict__ MU2) {
  const int row = blockIdx.x * 256 + threadIdx.x;
  float s = 0.f, ss = 0.f;
#pragma unroll
  for (int i = 0; i < 16; ++i) {
    float2 p = *(const float2*)&STATS[((size_t)row << 5) + i * 2];
    s += p.x; ss += p.y;
  }
  const float mu = s * (1.f / CH);
  const float var = ss * (1.f / CH) - mu * mu;
  MU2[row] = make_float2(mu, 1.f / sqrtf(var + 1e-5f));
}

// ---------------------------------------------------------------------------
// K3: fused Z = relu(LN(H)) @ W2 + b2 -> per-head LSE -> Z, EXh/EXl, SELF.
// R7 8-wave structure (BM=64, BN=256, BK=32, 512 thr, 80KB dbuf LDS) with
// 2-DEEP A register pipeline: A_LOAD(kt+2) issued each iter; LN_WRITE(kt+1)
// consumes data loaded one full iteration earlier. Loop unrolled x2 so both
// register sets are statically indexed.
// Chunk regions/buf: Ah [0,256), Al [256,512), Bh [512,1536), Bl [1536,2560)
// ---------------------------------------------------------------------------
__global__ __launch_bounds__(512) void k_gemm2(const u16* __restrict__ Hh, const u16* __restrict__ Hl,
                                               const u16* __restrict__ W2ht, const u16* __restrict__ W2lt,
                                               const float* __restrict__ lng, const float* __restrict__ lnb,
                                               const float2* __restrict__ MU2,
                                               const float* __restrict__ b2,
                                               float* __restrict__ Z,
                                               u16* __restrict__ EXh, u16* __restrict__ EXl,
                                               float* __restrict__ SELF) {
  __shared__ u16 sm[2][2560 * 8];   // 80 KB
  __shared__ float selfp[64][4];
  const int tid = threadIdx.x;
  const int lane = tid & 63, w = tid >> 6;
  const int wr = w >> 2, wc = w & 3;
  const int gm = blockIdx.x * 64;
  const int st_row = lane >> 2;                     // B staging row-in-group
  const int st_k16 = (lane & 3) ^ ((lane >> 3) & 3);

  // A site for waves 0-3: site = tid in [0,256): row=site>>2 (0..63), kc=site&3
  const int arow = tid >> 2, akc = tid & 3;
  const int pcA = (arow >> 4) * 64 + (arow & 15) * 4 + (akc ^ ((arow >> 1) & 3));
  float2 murv = make_float2(0.f, 0.f);
  const u16 *gHh = nullptr, *gHl = nullptr;
  if (tid < 256) {
    murv = MU2[gm + arow];
    gHh = Hh + ((size_t)(gm + arow) << 11) + akc * 8;
    gHl = Hl + ((size_t)(gm + arow) << 11) + akc * 8;
  }

  f32x4 acc[2][4];
#pragma unroll
  for (int i = 0; i < 2; ++i)
#pragma unroll
    for (int j = 0; j < 4; ++j) acc[i][j] = (f32x4){0.f, 0.f, 0.f, 0.f};

  // two named A-register sets (even/odd kt) -- statically indexed (rule #20)
  uint4 hwA, lwA, hwB, lwB;
  auto A_LOAD_A = [&](int kt) {   // even kt -> regs A
    if (tid < 256) { hwA = *(const uint4*)(gHh + kt * 32); lwA = *(const uint4*)(gHl + kt * 32); }
  };
  auto A_LOAD_B = [&](int kt) {   // odd kt -> regs B
    if (tid < 256) { hwB = *(const uint4*)(gHh + kt * 32); lwB = *(const uint4*)(gHl + kt * 32); }
  };
  auto B_STAGE = [&](int buf, int kt) {
    if (w >= 4) {
#pragma unroll
      for (int t = 0; t < 8; ++t) {
        const int f = (w - 4) * 8 + t;          // [0,32)
        const int g = (f < 16) ? f : f - 16;    // group in matrix
        const u16* src = (f < 16) ? W2ht : W2lt;
        const int slot = ((f < 16) ? 512 + f * 64 : 1536 + (f - 16) * 64) + lane;
        const int row = g * 16 + st_row;
        gload16(src + ((size_t)row << 11) + (kt << 5) + st_k16 * 8,
                &sm[buf][(size_t)slot * 8]);
      }
    }
  };
  auto LN_WRITE = [&](int buf, int kt, const uint4& hwreg, const uint4& lwreg) {
    if (tid < 256) {
      const int kb = kt * 32 + akc * 8;
      float4 g0 = *(const float4*)&lng[kb];
      float4 g1 = *(const float4*)&lng[kb + 4];
      float4 bb0 = *(const float4*)&lnb[kb];
      float4 bb1 = *(const float4*)&lnb[kb + 4];
      const float gg[8] = {g0.x, g0.y, g0.z, g0.w, g1.x, g1.y, g1.z, g1.w};
      const float bb[8] = {bb0.x, bb0.y, bb0.z, bb0.w, bb1.x, bb1.y, bb1.z, bb1.w};
      const unsigned hws[4] = {hwreg.x, hwreg.y, hwreg.z, hwreg.w};
      const unsigned lws[4] = {lwreg.x, lwreg.y, lwreg.z, lwreg.w};
      unsigned oh[4], ol[4];
#pragma unroll
      for (int p = 0; p < 4; ++p) {
        u16 yh[2], yl[2];
#pragma unroll
        for (int e = 0; e < 2; ++e) {
          const u16 hu = (u16)(hws[p] >> (16 * e));
          const u16 lu = (u16)(lws[p] >> (16 * e));
          const float h = bf2f(hu) + bf2f(lu);
          const float a1 = murv.y * gg[2 * p + e];
          const float y = fmaxf(fmaf(h, a1, bb[2 * p + e] - murv.x * a1), 0.f);
          yh[e] = f2bf(y);
          yl[e] = f2bf(y - bf2f(yh[e]));
        }
        oh[p] = (unsigned)yh[0] | ((unsigned)yh[1] << 16);
        ol[p] = (unsigned)yl[0] | ((unsigned)yl[1] << 16);
      }
      *(uint4*)&sm[buf][(size_t)pcA * 8] = make_uint4(oh[0], oh[1], oh[2], oh[3]);
      *(uint4*)&sm[buf][(size_t)(256 + pcA) * 8] = make_uint4(ol[0], ol[1], ol[2], ol[3]);
    }
  };

  const int lr = lane & 15;
  const int rI = lr * 4 + ((lane >> 4) ^ ((lr >> 1) & 3));

  auto MFMA_STEP = [&](const u16* base) {
    short8 ah[2], al[2], bh[4], bl[4];
#pragma unroll
    for (int i = 0; i < 2; ++i) {
      ah[i] = *(const short8*)(base + ((wr * 2 + i) * 64 + rI) * 8);
      al[i] = *(const short8*)(base + (256 + (wr * 2 + i) * 64 + rI) * 8);
    }
#pragma unroll
    for (int j = 0; j < 4; ++j) {
      bh[j] = *(const short8*)(base + (512 + (wc * 4 + j) * 64 + rI) * 8);
      bl[j] = *(const short8*)(base + (1536 + (wc * 4 + j) * 64 + rI) * 8);
    }
#pragma unroll
    for (int i = 0; i < 2; ++i)
#pragma unroll
      for (int j = 0; j < 4; ++j) {
        acc[i][j] = __builtin_amdgcn_mfma_f32_16x16x32_bf16(ah[i], bh[j], acc[i][j], 0, 0, 0);
        acc[i][j] = __builtin_amdgcn_mfma_f32_16x16x32_bf16(ah[i], bl[j], acc[i][j], 0, 0, 0);
        acc[i][j] = __builtin_amdgcn_mfma_f32_16x16x32_bf16(al[i], bh[j], acc[i][j], 0, 0, 0);
      }
  };

  // prologue: A(0) consumed immediately into buf0; A(1) in flight (regs B)
  A_LOAD_A(0);
  B_STAGE(0, 0);
  LN_WRITE(0, 0, hwA, lwA);
  A_LOAD_B(1);

  for (int kt = 0; kt < 64; kt += 2) {
    // ---- even sub-iter (kt): compute buf0; prep buf1 ----
    __syncthreads();                     // buf0 ready
    if (kt + 2 < 64) A_LOAD_A(kt + 2);   // regs A free (consumed for buf(kt))
    B_STAGE(1, kt + 1);
    MFMA_STEP(sm[0]);
    LN_WRITE(1, kt + 1, hwB, lwB);       // A(kt+1): loaded one full iter ago
    // ---- odd sub-iter (kt+1): compute buf1; prep buf0 ----
    __syncthreads();                     // buf1 ready
    if (kt + 3 < 64) A_LOAD_B(kt + 3);
    if (kt + 2 < 64) B_STAGE(0, kt + 2);
    MFMA_STEP(sm[1]);
    if (kt + 2 < 64) LN_WRITE(0, kt + 2, hwA, lwA);
  }

  // fused epilogue: bias + per-head (64-col == this wave's wc) LSE
  const int cc = lane & 15;
  float bias[4];
#pragma unroll
  for (int j = 0; j < 4; ++j) bias[j] = b2[wc * 64 + j * 16 + cc];

#pragma unroll
  for (int i = 0; i < 2; ++i)
#pragma unroll
    for (int reg = 0; reg < 4; ++reg) {
      const int rl = wr * 32 + i * 16 + ((lane >> 4) << 2) + reg;   // row in [0,64)
      const int row = gm + rl;
      float z[4];
#pragma unroll
      for (int j = 0; j < 4; ++j) z[j] = acc[i][j][reg] + bias[j];
      float mx = fmaxf(fmaxf(z[0], z[1]), fmaxf(z[2], z[3]));
#pragma unroll
      for (int m = 1; m <= 8; m <<= 1) mx = fmaxf(mx, __shfl_xor(mx, m));
      float se = expf(z[0] - mx) + expf(z[1] - mx) + expf(z[2] - mx) + expf(z[3] - mx);
#pragma unroll
      for (int m = 1; m <= 8; m <<= 1) se += __shfl_xor(se, m);
      const float lse = mx + logf(se);
      float selfc = 0.f;
#pragma unroll
      for (int j = 0; j < 4; ++j) {
        const float p = z[j] - lse;
        const float e = expf(p);
        selfc += e * p;
        const size_t o = (size_t)row * DD + wc * 64 + j * 16 + cc;
        Z[o] = z[j];
        u16 h = f2bf(e);
        EXh[o] = h;
        EXl[o] = f2bf(e - bf2f(h));
      }
#pragma unroll
      for (int m = 1; m <= 8; m <<= 1) selfc += __shfl_xor(selfc, m);
      if (cc == 0) selfp[rl][wc] = selfc;
    }
  __syncthreads();
  if (tid < 64)
    SELF[gm + tid] = selfp[tid][0] + selfp[tid][1] + selfp[tid][2] + selfp[tid][3];
}

// ---------------------------------------------------------------------------
// K4: logE = log(emb), 3-split bf16 (hi/mid/lo), layout [1024][256]
// ---------------------------------------------------------------------------
__global__ __launch_bounds__(256) void k_prep_le(const float* __restrict__ E,
                                                 u16* __restrict__ LEh, u16* __restrict__ LEm,
                                                 u16* __restrict__ LEl) {
  const size_t i = ((size_t)blockIdx.x * 256 + threadIdx.x) * 4;
  float4 v4 = *(const float4*)&E[i];
  float v[4] = {logf(v4.x), logf(v4.y), logf(v4.z), logf(v4.w)};
  u16 h[4], m_[4], l[4];
#pragma unroll
  for (int e = 0; e < 4; ++e) {
    h[e] = f2bf(v[e]);
    float r1 = v[e] - bf2f(h[e]);
    m_[e] = f2bf(r1);
    float r2 = r1 - bf2f(m_[e]);
    l[e] = f2bf(r2);
  }
  *(uint2*)&LEh[i] = make_uint2((unsigned)h[0] | ((unsigned)h[1] << 16), (unsigned)h[2] | ((unsigned)h[3] << 16));
  *(uint2*)&LEm[i] = make_uint2((unsigned)m_[0] | ((unsigned)m_[1] << 16), (unsigned)m_[2] | ((unsigned)m_[3] << 16));
  *(uint2*)&LEl[i] = make_uint2((unsigned)l[0] | ((unsigned)l[1] << 16), (unsigned)l[2] | ((unsigned)l[3] << 16));
}

// ---------------------------------------------------------------------------
// K5: dots = EX @ LE^T (5-term split MFMA) with FUSED per-tile argmax.
// R7-proven version: 128x128 tile, single buffer, PV/PI [N][16].
// Regions: EXh 0, EXl 512, LEh 1024, LEm 1536, LEl 2048
// ---------------------------------------------------------------------------
__global__ __launch_bounds__(256) void k_dots(const u16* __restrict__ EXh, const u16* __restrict__ EXl,
                                              const u16* __restrict__ LEh, const u16* __restrict__ LEm,
                                              const u16* __restrict__ LEl,
                                              float* __restrict__ PV, int* __restrict__ PI) {
  __shared__ u16 sm[2560 * 8];
  const int tid = threadIdx.x;
  const int lane = tid & 63, w = tid >> 6;
  const int wr = w >> 1, wc = w & 1;
  const int gm = blockIdx.y * 128, m0 = blockIdx.x * 128;
  const int st_row = lane >> 2;
  const int st_k16 = (lane & 3) ^ ((lane >> 3) & 3);

  f32x4 acc[4][4];
#pragma unroll
  for (int i = 0; i < 4; ++i)
#pragma unroll
    for (int j = 0; j < 4; ++j) acc[i][j] = (f32x4){0.f, 0.f, 0.f, 0.f};

  const int rI = (lane & 15) * 4 + ((lane >> 4) ^ ((lane >> 1) & 3));
  for (int kt = 0; kt < 8; ++kt) {
    __syncthreads();
#pragma unroll
    for (int t = 0; t < 10; ++t) {
      const int f = w * 10 + t;
      const int mtx = f >> 3, tm = f & 7;
      const u16* src = (mtx == 0) ? EXh : (mtx == 1) ? EXl :
                       (mtx == 2) ? LEh : (mtx == 3) ? LEm : LEl;
      const int rowbase = (mtx < 2) ? gm : m0;
      const int row = rowbase + tm * 16 + st_row;
      const u16* g = src + ((size_t)row << 8) + (kt << 5) + st_k16 * 8;
      gload16(g, &sm[(f * 64 + lane) * 8]);
    }
    __syncthreads();
    short8 eh[4], el[4], bh[4], bm[4], bl[4];
#pragma unroll
    for (int i = 0; i < 4; ++i) {
      eh[i] = *(const short8*)(sm + ((wr * 4 + i) * 64 + rI) * 8);
      el[i] = *(const short8*)(sm + (512 + (wr * 4 + i) * 64 + rI) * 8);
      bh[i] = *(const short8*)(sm + (1024 + (wc * 4 + i) * 64 + rI) * 8);
      bm[i] = *(const short8*)(sm + (1536 + (wc * 4 + i) * 64 + rI) * 8);
      bl[i] = *(const short8*)(sm + (2048 + (wc * 4 + i) * 64 + rI) * 8);
    }
#pragma unroll
    for (int i = 0; i < 4; ++i)
#pragma unroll
      for (int j = 0; j < 4; ++j) {
        acc[i][j] = __builtin_amdgcn_mfma_f32_16x16x32_bf16(eh[i], bh[j], acc[i][j], 0, 0, 0);
        acc[i][j] = __builtin_amdgcn_mfma_f32_16x16x32_bf16(eh[i], bm[j], acc[i][j], 0, 0, 0);
        acc[i][j] = __builtin_amdgcn_mfma_f32_16x16x32_bf16(eh[i], bl[j], acc[i][j], 0, 0, 0);
        acc[i][j] = __builtin_amdgcn_mfma_f32_16x16x32_bf16(el[i], bh[j], acc[i][j], 0, 0, 0);
        acc[i][j] = __builtin_amdgcn_mfma_f32_16x16x32_bf16(el[i], bm[j], acc[i][j], 0, 0, 0);
      }
  }

  const int cc = lane & 15;
  const int mtile = blockIdx.x * 2 + wc;
#pragma unroll
  for (int i = 0; i < 4; ++i)
#pragma unroll
    for (int reg = 0; reg < 4; ++reg) {
      float bv = acc[i][0][reg];
      int bi = m0 + wc * 64 + cc;
#pragma unroll
      for (int j = 1; j < 4; ++j) {
        const float v = acc[i][j][reg];
        if (v > bv) { bv = v; bi = m0 + wc * 64 + j * 16 + cc; }
      }
#pragma unroll
      for (int msk = 8; msk; msk >>= 1) {
        const float ov = __shfl_xor(bv, msk);
        const int   oi = __shfl_xor(bi, msk);
        if (ov > bv || (ov == bv && oi < bi)) { bv = ov; bi = oi; }
      }
      if (cc == 0) {
        const int row = gm + wr * 64 + i * 16 + ((lane >> 4) << 2) + reg;
        PV[row * 16 + mtile] = bv;
        PI[row * 16 + mtile] = bi;
      }
    }
}

// ---------------------------------------------------------------------------
// K6: per row: reduce 16 partials, KL = self - best, gather Q. Wave per row.
// ---------------------------------------------------------------------------
__global__ __launch_bounds__(256) void k_scan(const float* __restrict__ PV,
                                              const int* __restrict__ PI,
                                              const float* __restrict__ SELF,
                                              const float* __restrict__ E,
                                              float* __restrict__ Q,
                                              float* __restrict__ KL) {
  const int tid = threadIdx.x;
  const int lane = tid & 63;
  const int row = blockIdx.x * 4 + (tid >> 6);

  float bv = -1e30f;
  int bi = 0x7fffffff;
  if (lane < 16) { bv = PV[row * 16 + lane]; bi = PI[row * 16 + lane]; }
#pragma unroll
  for (int m = 32; m; m >>= 1) {
    const float ov = __shfl_xor(bv, m);
    const int   oi = __shfl_xor(bi, m);
    if (ov > bv || (ov == bv && oi < bi)) { bv = ov; bi = oi; }
  }
  if (lane == 0) KL[row] = SELF[row] - bv;
  float4 e4 = *(const float4*)&E[((size_t)bi << 8) + lane * 4];
  *(float4*)&Q[((size_t)row << 8) + lane * 4] = e4;
}

// ---------------------------------------------------------------------------
// K7: loss = 0.25/B * sum_n kl[n]*mask[n]
// ---------------------------------------------------------------------------
__global__ __launch_bounds__(256) void k_loss(const float* __restrict__ KL,
                                              const float* __restrict__ MASK,
                                              float* __restrict__ out) {
  __shared__ float red[4];
  const int tid = threadIdx.x;
  float s = 0.f;
  for (int i = tid; i < NROWS; i += 256) s += KL[i] * MASK[i];
#pragma unroll
  for (int m = 32; m; m >>= 1) s += __shfl_xor(s, m);
  if ((tid & 63) == 0) red[tid >> 6] = s;
  __syncthreads();
  if (tid == 0) out[0] = (red[0] + red[1] + red[2] + red[3]) * (0.25f / 16.f);
}

// ---------------------------------------------------------------------------
extern "C" void kernel_launch(void* const* d_in, const int* in_sizes, int n_in,
                              void* d_out, int out_size, void* d_ws, size_t ws_size,
                              hipStream_t stream) {
  const float* x     = (const float*)d_in[0];
  const float* masks = (const float*)d_in[1];
  const float* W1    = (const float*)d_in[2];
  const float* ln_g  = (const float*)d_in[3];
  const float* ln_b  = (const float*)d_in[4];
  const float* W2    = (const float*)d_in[5];
  const float* b2    = (const float*)d_in[6];
  const float* emb   = (const float*)d_in[7];

  float* z_out = (float*)d_out;
  float* q_out = z_out + (size_t)NROWS * DD;
  float* loss_out = z_out + 2 * (size_t)NROWS * DD;

  char* ws = (char*)d_ws;
  u16*   Hh   = (u16*)(ws);                    //  67,108,864 (16384x2048)
  u16*   Hl   = (u16*)(ws + 67108864);         //  67,108,864
  u16*   W1ht = (u16*)(ws + 134217728);        //   2,097,152
  u16*   W1lt = (u16*)(ws + 136314880);        //   2,097,152
  u16*   W2ht = (u16*)(ws + 138412032);        //   1,048,576
  u16*   W2lt = (u16*)(ws + 139460608);        //   1,048,576
  u16*   LEh  = (u16*)(ws + 140509184);        //     524,288
  u16*   LEm  = (u16*)(ws + 141033472);        //     524,288
  u16*   LEl  = (u16*)(ws + 141557760);        //     524,288
  float* SELF = (float*)(ws + 142082048);      //      65,536
  float* KL   = (float*)(ws + 142147584);      //      65,536
  u16*   Xh   = (u16*)(ws + 142213120);        //   4,194,304 (quarter 4096x512)
  u16*   Xl   = (u16*)(ws + 146407424);        //   4,194,304
  float2* MU2 = (float2*)(ws + 150601728);     //     131,072 -> end 150,732,800
  // overlays:
  float* PV   = (float*)(ws);                  //   1 MB (over Hh; H dead after gemm2)
  int*   PI   = (int*)(ws + 1048576);          //   1 MB
  float* STATS = (float*)q_out;                //   2 MB (q_out; dead before EX written)
  u16*   EXh  = (u16*)q_out;                   //   8 MB (after STATS consumed)
  u16*   EXl  = EXh + (size_t)NROWS * DD;      //   8 MB

  k_split_wT<<<dim3(64, 16), 256, 0, stream>>>(W1, W1ht, W1lt, INCH, CH);
  k_split_wT<<<dim3(8, 64), 256, 0, stream>>>(W2, W2ht, W2lt, CH, DD);
  k_prep_le<<<256, 256, 0, stream>>>(emb, LEh, LEm, LEl);

  for (int q = 0; q < 4; ++q) {
    const size_t xo = (size_t)q * QROWS * INCH;
    const size_t ho = (size_t)q * QROWS * CH;
    k_split_x<<<1024, 256, 0, stream>>>(x + xo, Xh, Xl);
    k_gemm1<<<dim3(16, 32), 256, 0, stream>>>(Xh, Xl, W1ht, W1lt, Hh + ho, Hl + ho,
                                              STATS + (size_t)q * QROWS * 32);
  }
  k_rowstats<<<NROWS / 256, 256, 0, stream>>>(STATS, MU2);
  k_gemm2<<<NROWS / 64, 512, 0, stream>>>(Hh, Hl, W2ht, W2lt, ln_g, ln_b, MU2, b2,
                                          z_out, EXh, EXl, SELF);

  k_dots<<<dim3(8, 128), 256, 0, stream>>>(EXh, EXl, LEh, LEm, LEl, PV, PI);
  k_scan<<<4096, 256, 0, stream>>>(PV, PI, SELF, emb, q_out, KL);
  k_loss<<<1, 256, 0, stream>>>(KL, masks, loss_out);
}

// Round 11
// 335.293 us; speedup vs baseline: 1.3435x; 1.0820x over previous
//
#include <hip/hip_runtime.h>
#include <math.h>

#define NROWS 16384   // B*T
#define INCH  512
#define CH    2048
#define DD    256
#define MM    1024

typedef unsigned short u16;
typedef short short8 __attribute__((ext_vector_type(8)));
typedef float f32x4 __attribute__((ext_vector_type(4)));

__device__ __forceinline__ u16 f2bf(float f) {
  unsigned u = __float_as_uint(f);
  return (u16)((u + 0x7fffu + ((u >> 16) & 1u)) >> 16);
}
__device__ __forceinline__ float bf2f(u16 h) {
  return __uint_as_float(((unsigned)h) << 16);
}
__device__ __forceinline__ void gload16(const u16* g, u16* lds) {
  __builtin_amdgcn_global_load_lds((const __attribute__((address_space(1))) void*)g,
                                   (__attribute__((address_space(3))) void*)lds, 16, 0, 0);
}

// Coalesced-staging chunk mapping (16B chunks of 8 bf16 along K):
//   PC(row,kc) = (row>>4)*64 + (row&15)*4 + (kc ^ ((row>>1)&3))
//   frag read: chunk = group*64 + rI, rI = (lane&15)*4 + ((lane>>4)^((lane>>1)&3))

// src [R][C] fp32  ->  dh/dl [C][R] bf16 hi/lo   (transpose + split)
__global__ __launch_bounds__(256) void k_split_wT(const float* __restrict__ src,
                                                  u16* __restrict__ dh, u16* __restrict__ dl,
                                                  int R, int C) {
  __shared__ float t[32][33];
  const int tx = threadIdx.x & 31, ty = threadIdx.x >> 5;
  const int c0 = blockIdx.x * 32, r0 = blockIdx.y * 32;
#pragma unroll
  for (int i = 0; i < 4; ++i)
    t[ty + i * 8][tx] = src[(size_t)(r0 + ty + i * 8) * C + c0 + tx];
  __syncthreads();
#pragma unroll
  for (int i = 0; i < 4; ++i) {
    float v = t[tx][ty + i * 8];
    size_t o = (size_t)(c0 + ty + i * 8) * R + r0 + tx;
    u16 h = f2bf(v);
    dh[o] = h;
    dl[o] = f2bf(v - bf2f(h));
  }
}

// ---------------------------------------------------------------------------
// K1: H(split) = X @ W1.  Tile 256x256, BK=32, 512 thr (8 waves 2Mx4N),
// wave tile 128x64 (MFMA:ds_read = 4:1). A: fp32 global->reg->split->ds_write
// (k_split_x folded in). B: pre-split W1^T via global_load_lds.
// LDS 128KB dbuf. Regions/buf (chunks): Ah[0,1024) Al[1024,2048) Bh[2048,3072)
// Bl[3072,4096). Epilogue: 4x 64-row slabs via fp32 [64][260] + row stats.
// ---------------------------------------------------------------------------
__global__ __launch_bounds__(512, 2) void k_gemm1(const float* __restrict__ X,
                                                  const u16* __restrict__ W1ht,
                                                  const u16* __restrict__ W1lt,
                                                  u16* __restrict__ Hh, u16* __restrict__ Hl,
                                                  float* __restrict__ STATS) {
  __shared__ u16 sm[2][4096 * 8];   // 128 KB
  const int tid = threadIdx.x;
  const int lane = tid & 63, w = tid >> 6;
  const int wr = w >> 2, wc = w & 3;
  const int gm = blockIdx.y * 256, n0 = blockIdx.x * 256;

  // A staging site: row arow (0..255), half ahalf (16 k-elems each)
  const int arow = tid >> 1, ahalf = tid & 1;
  const float* gx = X + ((size_t)(gm + arow) << 9) + ahalf * 16;
  const int axor = (arow >> 1) & 3;
  const int pcbase = (arow >> 4) * 64 + (arow & 15) * 4;

  f32x4 acc[8][4];
#pragma unroll
  for (int i = 0; i < 8; ++i)
#pragma unroll
    for (int j = 0; j < 4; ++j) acc[i][j] = (f32x4){0.f, 0.f, 0.f, 0.f};

  float a16[16];
  auto A_LOAD = [&](int kt) {
    const float* p = gx + kt * 32;
    *(float4*)&a16[0]  = *(const float4*)(p);
    *(float4*)&a16[4]  = *(const float4*)(p + 4);
    *(float4*)&a16[8]  = *(const float4*)(p + 8);
    *(float4*)&a16[12] = *(const float4*)(p + 12);
  };
  auto A_WRITE = [&](int buf) {
#pragma unroll
    for (int g = 0; g < 2; ++g) {
      const int kc = ahalf * 2 + g;
      unsigned hw[4], lw[4];
#pragma unroll
      for (int p = 0; p < 4; ++p) {
        const float v0 = a16[g * 8 + 2 * p], v1 = a16[g * 8 + 2 * p + 1];
        const u16 h0 = f2bf(v0), h1 = f2bf(v1);
        const u16 l0 = f2bf(v0 - bf2f(h0)), l1 = f2bf(v1 - bf2f(h1));
        hw[p] = (unsigned)h0 | ((unsigned)h1 << 16);
        lw[p] = (unsigned)l0 | ((unsigned)l1 << 16);
      }
      const int pc = pcbase + (kc ^ axor);
      *(uint4*)&sm[buf][(size_t)pc * 8] = make_uint4(hw[0], hw[1], hw[2], hw[3]);
      *(uint4*)&sm[buf][(size_t)(1024 + pc) * 8] = make_uint4(lw[0], lw[1], lw[2], lw[3]);
    }
  };
  auto B_STAGE = [&](int buf, int kt) {
#pragma unroll
    for (int t = 0; t < 4; ++t) {
      const int f = t * 512 + tid;            // [0,2048)
      const int mtx = f >> 10;                // 0: Bh, 1: Bl (wave-uniform)
      const int wi = f & 1023;
      const int grp = wi >> 6, s2 = wi & 63;
      const int srow = n0 + grp * 16 + (s2 >> 2);
      const int k16 = (s2 & 3) ^ ((s2 >> 3) & 3);
      const u16* src = mtx ? W1lt : W1ht;
      gload16(src + ((size_t)srow << 9) + (kt << 5) + k16 * 8,
              &sm[buf][(size_t)(2048 + f) * 8]);
    }
  };

  A_LOAD(0);
  B_STAGE(0, 0);
  A_WRITE(0);

  const int lr = lane & 15;
  const int rI = lr * 4 + ((lane >> 4) ^ ((lr >> 1) & 3));
  for (int kt = 0; kt < 16; ++kt) {
    __syncthreads();
    if (kt + 1 < 16) {
      A_LOAD(kt + 1);
      B_STAGE((kt + 1) & 1, kt + 1);
    }
    const u16* base = sm[kt & 1];
    short8 bh[4], bl[4];
#pragma unroll
    for (int j = 0; j < 4; ++j) {
      bh[j] = *(const short8*)(base + (size_t)(2048 + (wc * 4 + j) * 64 + rI) * 8);
      bl[j] = *(const short8*)(base + (size_t)(3072 + (wc * 4 + j) * 64 + rI) * 8);
    }
#pragma unroll
    for (int i = 0; i < 8; ++i) {
      short8 ah = *(const short8*)(base + (size_t)((wr * 8 + i) * 64 + rI) * 8);
      short8 al = *(const short8*)(base + (size_t)(1024 + (wr * 8 + i) * 64 + rI) * 8);
#pragma unroll
      for (int j = 0; j < 4; ++j) {
        acc[i][j] = __builtin_amdgcn_mfma_f32_16x16x32_bf16(ah, bh[j], acc[i][j], 0, 0, 0);
        acc[i][j] = __builtin_amdgcn_mfma_f32_16x16x32_bf16(ah, bl[j], acc[i][j], 0, 0, 0);
        acc[i][j] = __builtin_amdgcn_mfma_f32_16x16x32_bf16(al, bh[j], acc[i][j], 0, 0, 0);
      }
    }
    if (kt + 1 < 16) A_WRITE((kt + 1) & 1);
  }

  // ---- epilogue: 4 slabs of 64 rows via fp32 [64][260] (66.6 KB of sm) ----
  float* smf = (float*)&sm[0][0];
  const int rr = (lane >> 4) << 2, cc = lane & 15;
  const int lrow = tid >> 3, c0 = (tid & 7) * 32;
#pragma unroll
  for (int s = 0; s < 4; ++s) {
    __syncthreads();
    if (wr == (s >> 1)) {
      const int ib = (s & 1) * 4;
#pragma unroll
      for (int ii = 0; ii < 4; ++ii)
#pragma unroll
        for (int j = 0; j < 4; ++j)
#pragma unroll
          for (int reg = 0; reg < 4; ++reg)
            smf[(ii * 16 + rr + reg) * 260 + wc * 64 + j * 16 + cc] = acc[ib + ii][j][reg];
    }
    __syncthreads();
    const int grow = gm + s * 64 + lrow;
    float s1 = 0.f, ss = 0.f;
#pragma unroll
    for (int q = 0; q < 4; ++q) {
      float v[8];
      *(f32x4*)&v[0] = *(const f32x4*)&smf[lrow * 260 + c0 + q * 8];
      *(f32x4*)&v[4] = *(const f32x4*)&smf[lrow * 260 + c0 + q * 8 + 4];
#pragma unroll
      for (int e = 0; e < 8; ++e) { s1 += v[e]; ss += v[e] * v[e]; }
      unsigned hw[4], lw[4];
#pragma unroll
      for (int p = 0; p < 4; ++p) {
        const u16 h0 = f2bf(v[2 * p]), h1 = f2bf(v[2 * p + 1]);
        const u16 l0 = f2bf(v[2 * p] - bf2f(h0)), l1 = f2bf(v[2 * p + 1] - bf2f(h1));
        hw[p] = (unsigned)h0 | ((unsigned)h1 << 16);
        lw[p] = (unsigned)l0 | ((unsigned)l1 << 16);
      }
      const size_t o = (size_t)grow * CH + n0 + c0 + q * 8;
      *(uint4*)&Hh[o] = make_uint4(hw[0], hw[1], hw[2], hw[3]);
      *(uint4*)&Hl[o] = make_uint4(lw[0], lw[1], lw[2], lw[3]);
    }
#pragma unroll
    for (int m = 1; m <= 4; m <<= 1) { s1 += __shfl_xor(s1, m); ss += __shfl_xor(ss, m); }
    if ((tid & 7) == 0)
      *(float2*)&STATS[(size_t)grow * 16 + blockIdx.x * 2] = make_float2(s1, ss);
  }
}

// ---------------------------------------------------------------------------
// K2: reduce 8 slice-partials per row -> (mu, rinv)
// ---------------------------------------------------------------------------
__global__ __launch_bounds__(256) void k_rowstats(const float* __restrict__ STATS,
                                                  float2* __restrict__ MU2) {
  const int row = blockIdx.x * 256 + threadIdx.x;
  float s = 0.f, ss = 0.f;
#pragma unroll
  for (int i = 0; i < 8; ++i) {
    float2 p = *(const float2*)&STATS[((size_t)row << 4) + i * 2];
    s += p.x; ss += p.y;
  }
  const float mu = s * (1.f / CH);
  const float var = ss * (1.f / CH) - mu * mu;
  MU2[row] = make_float2(mu, 1.f / sqrtf(var + 1e-5f));
}

// ---------------------------------------------------------------------------
// K3: fused Z = relu(LN(H)) @ W2 + b2 -> per-head LSE -> Z, EXh/EXl, SELF.
// 8-wave structure (BM=64, BN=256, BK=32, 512 thr, 80KB dbuf LDS) with
// 2-deep A register pipeline (R9).
// ---------------------------------------------------------------------------
__global__ __launch_bounds__(512) void k_gemm2(const u16* __restrict__ Hh, const u16* __restrict__ Hl,
                                               const u16* __restrict__ W2ht, const u16* __restrict__ W2lt,
                                               const float* __restrict__ lng, const float* __restrict__ lnb,
                                               const float2* __restrict__ MU2,
                                               const float* __restrict__ b2,
                                               float* __restrict__ Z,
                                               u16* __restrict__ EXh, u16* __restrict__ EXl,
                                               float* __restrict__ SELF) {
  __shared__ u16 sm[2][2560 * 8];   // 80 KB
  __shared__ float selfp[64][4];
  const int tid = threadIdx.x;
  const int lane = tid & 63, w = tid >> 6;
  const int wr = w >> 2, wc = w & 3;
  const int gm = blockIdx.x * 64;
  const int st_row = lane >> 2;
  const int st_k16 = (lane & 3) ^ ((lane >> 3) & 3);

  const int arow = tid >> 2, akc = tid & 3;
  const int pcA = (arow >> 4) * 64 + (arow & 15) * 4 + (akc ^ ((arow >> 1) & 3));
  float2 murv = make_float2(0.f, 0.f);
  const u16 *gHh = nullptr, *gHl = nullptr;
  if (tid < 256) {
    murv = MU2[gm + arow];
    gHh = Hh + ((size_t)(gm + arow) << 11) + akc * 8;
    gHl = Hl + ((size_t)(gm + arow) << 11) + akc * 8;
  }

  f32x4 acc[2][4];
#pragma unroll
  for (int i = 0; i < 2; ++i)
#pragma unroll
    for (int j = 0; j < 4; ++j) acc[i][j] = (f32x4){0.f, 0.f, 0.f, 0.f};

  uint4 hwA, lwA, hwB, lwB;
  auto A_LOAD_A = [&](int kt) {
    if (tid < 256) { hwA = *(const uint4*)(gHh + kt * 32); lwA = *(const uint4*)(gHl + kt * 32); }
  };
  auto A_LOAD_B = [&](int kt) {
    if (tid < 256) { hwB = *(const uint4*)(gHh + kt * 32); lwB = *(const uint4*)(gHl + kt * 32); }
  };
  auto B_STAGE = [&](int buf, int kt) {
    if (w >= 4) {
#pragma unroll
      for (int t = 0; t < 8; ++t) {
        const int f = (w - 4) * 8 + t;
        const int g = (f < 16) ? f : f - 16;
        const u16* src = (f < 16) ? W2ht : W2lt;
        const int slot = ((f < 16) ? 512 + f * 64 : 1536 + (f - 16) * 64) + lane;
        const int row = g * 16 + st_row;
        gload16(src + ((size_t)row << 11) + (kt << 5) + st_k16 * 8,
                &sm[buf][(size_t)slot * 8]);
      }
    }
  };
  auto LN_WRITE = [&](int buf, int kt, const uint4& hwreg, const uint4& lwreg) {
    if (tid < 256) {
      const int kb = kt * 32 + akc * 8;
      float4 g0 = *(const float4*)&lng[kb];
      float4 g1 = *(const float4*)&lng[kb + 4];
      float4 bb0 = *(const float4*)&lnb[kb];
      float4 bb1 = *(const float4*)&lnb[kb + 4];
      const float gg[8] = {g0.x, g0.y, g0.z, g0.w, g1.x, g1.y, g1.z, g1.w};
      const float bb[8] = {bb0.x, bb0.y, bb0.z, bb0.w, bb1.x, bb1.y, bb1.z, bb1.w};
      const unsigned hws[4] = {hwreg.x, hwreg.y, hwreg.z, hwreg.w};
      const unsigned lws[4] = {lwreg.x, lwreg.y, lwreg.z, lwreg.w};
      unsigned oh[4], ol[4];
#pragma unroll
      for (int p = 0; p < 4; ++p) {
        u16 yh[2], yl[2];
#pragma unroll
        for (int e = 0; e < 2; ++e) {
          const u16 hu = (u16)(hws[p] >> (16 * e));
          const u16 lu = (u16)(lws[p] >> (16 * e));
          const float h = bf2f(hu) + bf2f(lu);
          const float a1 = murv.y * gg[2 * p + e];
          const float y = fmaxf(fmaf(h, a1, bb[2 * p + e] - murv.x * a1), 0.f);
          yh[e] = f2bf(y);
          yl[e] = f2bf(y - bf2f(yh[e]));
        }
        oh[p] = (unsigned)yh[0] | ((unsigned)yh[1] << 16);
        ol[p] = (unsigned)yl[0] | ((unsigned)yl[1] << 16);
      }
      *(uint4*)&sm[buf][(size_t)pcA * 8] = make_uint4(oh[0], oh[1], oh[2], oh[3]);
      *(uint4*)&sm[buf][(size_t)(256 + pcA) * 8] = make_uint4(ol[0], ol[1], ol[2], ol[3]);
    }
  };

  const int lr = lane & 15;
  const int rI = lr * 4 + ((lane >> 4) ^ ((lr >> 1) & 3));

  auto MFMA_STEP = [&](const u16* base) {
    short8 ah[2], al[2], bh[4], bl[4];
#pragma unroll
    for (int i = 0; i < 2; ++i) {
      ah[i] = *(const short8*)(base + ((wr * 2 + i) * 64 + rI) * 8);
      al[i] = *(const short8*)(base + (256 + (wr * 2 + i) * 64 + rI) * 8);
    }
#pragma unroll
    for (int j = 0; j < 4; ++j) {
      bh[j] = *(const short8*)(base + (512 + (wc * 4 + j) * 64 + rI) * 8);
      bl[j] = *(const short8*)(base + (1536 + (wc * 4 + j) * 64 + rI) * 8);
    }
#pragma unroll
    for (int i = 0; i < 2; ++i)
#pragma unroll
      for (int j = 0; j < 4; ++j) {
        acc[i][j] = __builtin_amdgcn_mfma_f32_16x16x32_bf16(ah[i], bh[j], acc[i][j], 0, 0, 0);
        acc[i][j] = __builtin_amdgcn_mfma_f32_16x16x32_bf16(ah[i], bl[j], acc[i][j], 0, 0, 0);
        acc[i][j] = __builtin_amdgcn_mfma_f32_16x16x32_bf16(al[i], bh[j], acc[i][j], 0, 0, 0);
      }
  };

  A_LOAD_A(0);
  B_STAGE(0, 0);
  LN_WRITE(0, 0, hwA, lwA);
  A_LOAD_B(1);

  for (int kt = 0; kt < 64; kt += 2) {
    __syncthreads();
    if (kt + 2 < 64) A_LOAD_A(kt + 2);
    B_STAGE(1, kt + 1);
    MFMA_STEP(sm[0]);
    LN_WRITE(1, kt + 1, hwB, lwB);
    __syncthreads();
    if (kt + 3 < 64) A_LOAD_B(kt + 3);
    if (kt + 2 < 64) B_STAGE(0, kt + 2);
    MFMA_STEP(sm[1]);
    if (kt + 2 < 64) LN_WRITE(0, kt + 2, hwA, lwA);
  }

  const int cc = lane & 15;
  float bias[4];
#pragma unroll
  for (int j = 0; j < 4; ++j) bias[j] = b2[wc * 64 + j * 16 + cc];

#pragma unroll
  for (int i = 0; i < 2; ++i)
#pragma unroll
    for (int reg = 0; reg < 4; ++reg) {
      const int rl = wr * 32 + i * 16 + ((lane >> 4) << 2) + reg;
      const int row = gm + rl;
      float z[4];
#pragma unroll
      for (int j = 0; j < 4; ++j) z[j] = acc[i][j][reg] + bias[j];
      float mx = fmaxf(fmaxf(z[0], z[1]), fmaxf(z[2], z[3]));
#pragma unroll
      for (int m = 1; m <= 8; m <<= 1) mx = fmaxf(mx, __shfl_xor(mx, m));
      float se = expf(z[0] - mx) + expf(z[1] - mx) + expf(z[2] - mx) + expf(z[3] - mx);
#pragma unroll
      for (int m = 1; m <= 8; m <<= 1) se += __shfl_xor(se, m);
      const float lse = mx + logf(se);
      float selfc = 0.f;
#pragma unroll
      for (int j = 0; j < 4; ++j) {
        const float p = z[j] - lse;
        const float e = expf(p);
        selfc += e * p;
        const size_t o = (size_t)row * DD + wc * 64 + j * 16 + cc;
        Z[o] = z[j];
        u16 h = f2bf(e);
        EXh[o] = h;
        EXl[o] = f2bf(e - bf2f(h));
      }
#pragma unroll
      for (int m = 1; m <= 8; m <<= 1) selfc += __shfl_xor(selfc, m);
      if (cc == 0) selfp[rl][wc] = selfc;
    }
  __syncthreads();
  if (tid < 64)
    SELF[gm + tid] = selfp[tid][0] + selfp[tid][1] + selfp[tid][2] + selfp[tid][3];
}

// ---------------------------------------------------------------------------
// K4: logE = log(emb), 3-split bf16 (hi/mid/lo), layout [1024][256]
// ---------------------------------------------------------------------------
__global__ __launch_bounds__(256) void k_prep_le(const float* __restrict__ E,
                                                 u16* __restrict__ LEh, u16* __restrict__ LEm,
                                                 u16* __restrict__ LEl) {
  const size_t i = ((size_t)blockIdx.x * 256 + threadIdx.x) * 4;
  float4 v4 = *(const float4*)&E[i];
  float v[4] = {logf(v4.x), logf(v4.y), logf(v4.z), logf(v4.w)};
  u16 h[4], m_[4], l[4];
#pragma unroll
  for (int e = 0; e < 4; ++e) {
    h[e] = f2bf(v[e]);
    float r1 = v[e] - bf2f(h[e]);
    m_[e] = f2bf(r1);
    float r2 = r1 - bf2f(m_[e]);
    l[e] = f2bf(r2);
  }
  *(uint2*)&LEh[i] = make_uint2((unsigned)h[0] | ((unsigned)h[1] << 16), (unsigned)h[2] | ((unsigned)h[3] << 16));
  *(uint2*)&LEm[i] = make_uint2((unsigned)m_[0] | ((unsigned)m_[1] << 16), (unsigned)m_[2] | ((unsigned)m_[3] << 16));
  *(uint2*)&LEl[i] = make_uint2((unsigned)l[0] | ((unsigned)l[1] << 16), (unsigned)l[2] | ((unsigned)l[3] << 16));
}

// ---------------------------------------------------------------------------
// K5: dots = EX @ LE^T (5-term split MFMA) with FUSED per-tile argmax.
// 128x128 tile, single buffer, PV/PI [N][16].
// ---------------------------------------------------------------------------
__global__ __launch_bounds__(256) void k_dots(const u16* __restrict__ EXh, const u16* __restrict__ EXl,
                                              const u16* __restrict__ LEh, const u16* __restrict__ LEm,
                                              const u16* __restrict__ LEl,
                                              float* __restrict__ PV, int* __restrict__ PI) {
  __shared__ u16 sm[2560 * 8];
  const int tid = threadIdx.x;
  const int lane = tid & 63, w = tid >> 6;
  const int wr = w >> 1, wc = w & 1;
  const int gm = blockIdx.y * 128, m0 = blockIdx.x * 128;
  const int st_row = lane >> 2;
  const int st_k16 = (lane & 3) ^ ((lane >> 3) & 3);

  f32x4 acc[4][4];
#pragma unroll
  for (int i = 0; i < 4; ++i)
#pragma unroll
    for (int j = 0; j < 4; ++j) acc[i][j] = (f32x4){0.f, 0.f, 0.f, 0.f};

  const int rI = (lane & 15) * 4 + ((lane >> 4) ^ ((lane >> 1) & 3));
  for (int kt = 0; kt < 8; ++kt) {
    __syncthreads();
#pragma unroll
    for (int t = 0; t < 10; ++t) {
      const int f = w * 10 + t;
      const int mtx = f >> 3, tm = f & 7;
      const u16* src = (mtx == 0) ? EXh : (mtx == 1) ? EXl :
                       (mtx == 2) ? LEh : (mtx == 3) ? LEm : LEl;
      const int rowbase = (mtx < 2) ? gm : m0;
      const int row = rowbase + tm * 16 + st_row;
      const u16* g = src + ((size_t)row << 8) + (kt << 5) + st_k16 * 8;
      gload16(g, &sm[(f * 64 + lane) * 8]);
    }
    __syncthreads();
    short8 eh[4], el[4], bh[4], bm[4], bl[4];
#pragma unroll
    for (int i = 0; i < 4; ++i) {
      eh[i] = *(const short8*)(sm + ((wr * 4 + i) * 64 + rI) * 8);
      el[i] = *(const short8*)(sm + (512 + (wr * 4 + i) * 64 + rI) * 8);
      bh[i] = *(const short8*)(sm + (1024 + (wc * 4 + i) * 64 + rI) * 8);
      bm[i] = *(const short8*)(sm + (1536 + (wc * 4 + i) * 64 + rI) * 8);
      bl[i] = *(const short8*)(sm + (2048 + (wc * 4 + i) * 64 + rI) * 8);
    }
#pragma unroll
    for (int i = 0; i < 4; ++i)
#pragma unroll
      for (int j = 0; j < 4; ++j) {
        acc[i][j] = __builtin_amdgcn_mfma_f32_16x16x32_bf16(eh[i], bh[j], acc[i][j], 0, 0, 0);
        acc[i][j] = __builtin_amdgcn_mfma_f32_16x16x32_bf16(eh[i], bm[j], acc[i][j], 0, 0, 0);
        acc[i][j] = __builtin_amdgcn_mfma_f32_16x16x32_bf16(eh[i], bl[j], acc[i][j], 0, 0, 0);
        acc[i][j] = __builtin_amdgcn_mfma_f32_16x16x32_bf16(el[i], bh[j], acc[i][j], 0, 0, 0);
        acc[i][j] = __builtin_amdgcn_mfma_f32_16x16x32_bf16(el[i], bm[j], acc[i][j], 0, 0, 0);
      }
  }

  const int cc = lane & 15;
  const int mtile = blockIdx.x * 2 + wc;
#pragma unroll
  for (int i = 0; i < 4; ++i)
#pragma unroll
    for (int reg = 0; reg < 4; ++reg) {
      float bv = acc[i][0][reg];
      int bi = m0 + wc * 64 + cc;
#pragma unroll
      for (int j = 1; j < 4; ++j) {
        const float v = acc[i][j][reg];
        if (v > bv) { bv = v; bi = m0 + wc * 64 + j * 16 + cc; }
      }
#pragma unroll
      for (int msk = 8; msk; msk >>= 1) {
        const float ov = __shfl_xor(bv, msk);
        const int   oi = __shfl_xor(bi, msk);
        if (ov > bv || (ov == bv && oi < bi)) { bv = ov; bi = oi; }
      }
      if (cc == 0) {
        const int row = gm + wr * 64 + i * 16 + ((lane >> 4) << 2) + reg;
        PV[row * 16 + mtile] = bv;
        PI[row * 16 + mtile] = bi;
      }
    }
}

// ---------------------------------------------------------------------------
// K6: per row: reduce 16 partials, KL = self - best, gather Q. Wave per row.
// ---------------------------------------------------------------------------
__global__ __launch_bounds__(256) void k_scan(const float* __restrict__ PV,
                                              const int* __restrict__ PI,
                                              const float* __restrict__ SELF,
                                              const float* __restrict__ E,
                                              float* __restrict__ Q,
                                              float* __restrict__ KL) {
  const int tid = threadIdx.x;
  const int lane = tid & 63;
  const int row = blockIdx.x * 4 + (tid >> 6);

  float bv = -1e30f;
  int bi = 0x7fffffff;
  if (lane < 16) { bv = PV[row * 16 + lane]; bi = PI[row * 16 + lane]; }
#pragma unroll
  for (int m = 32; m; m >>= 1) {
    const float ov = __shfl_xor(bv, m);
    const int   oi = __shfl_xor(bi, m);
    if (ov > bv || (ov == bv && oi < bi)) { bv = ov; bi = oi; }
  }
  if (lane == 0) KL[row] = SELF[row] - bv;
  float4 e4 = *(const float4*)&E[((size_t)bi << 8) + lane * 4];
  *(float4*)&Q[((size_t)row << 8) + lane * 4] = e4;
}

// ---------------------------------------------------------------------------
// K7: loss = 0.25/B * sum_n kl[n]*mask[n]
// ---------------------------------------------------------------------------
__global__ __launch_bounds__(256) void k_loss(const float* __restrict__ KL,
                                              const float* __restrict__ MASK,
                                              float* __restrict__ out) {
  __shared__ float red[4];
  const int tid = threadIdx.x;
  float s = 0.f;
  for (int i = tid; i < NROWS; i += 256) s += KL[i] * MASK[i];
#pragma unroll
  for (int m = 32; m; m >>= 1) s += __shfl_xor(s, m);
  if ((tid & 63) == 0) red[tid >> 6] = s;
  __syncthreads();
  if (tid == 0) out[0] = (red[0] + red[1] + red[2] + red[3]) * (0.25f / 16.f);
}

// ---------------------------------------------------------------------------
extern "C" void kernel_launch(void* const* d_in, const int* in_sizes, int n_in,
                              void* d_out, int out_size, void* d_ws, size_t ws_size,
                              hipStream_t stream) {
  const float* x     = (const float*)d_in[0];
  const float* masks = (const float*)d_in[1];
  const float* W1    = (const float*)d_in[2];
  const float* ln_g  = (const float*)d_in[3];
  const float* ln_b  = (const float*)d_in[4];
  const float* W2    = (const float*)d_in[5];
  const float* b2    = (const float*)d_in[6];
  const float* emb   = (const float*)d_in[7];

  float* z_out = (float*)d_out;
  float* q_out = z_out + (size_t)NROWS * DD;
  float* loss_out = z_out + 2 * (size_t)NROWS * DD;

  char* ws = (char*)d_ws;
  u16*   Hh   = (u16*)(ws);                    //  67,108,864 (16384x2048)
  u16*   Hl   = (u16*)(ws + 67108864);         //  67,108,864
  u16*   W1ht = (u16*)(ws + 134217728);        //   2,097,152
  u16*   W1lt = (u16*)(ws + 136314880);        //   2,097,152
  u16*   W2ht = (u16*)(ws + 138412032);        //   1,048,576
  u16*   W2lt = (u16*)(ws + 139460608);        //   1,048,576
  u16*   LEh  = (u16*)(ws + 140509184);        //     524,288
  u16*   LEm  = (u16*)(ws + 141033472);        //     524,288
  u16*   LEl  = (u16*)(ws + 141557760);        //     524,288
  float* SELF = (float*)(ws + 142082048);      //      65,536
  float* KL   = (float*)(ws + 142147584);      //      65,536
  float2* MU2 = (float2*)(ws + 142213120);     //     131,072 -> end 142,344,192
  // overlays:
  float* PV   = (float*)(ws);                  //   1 MB (over Hh; H dead after gemm2)
  int*   PI   = (int*)(ws + 1048576);          //   1 MB
  float* STATS = (float*)q_out;                //   1 MB (q_out; dead before EX written)
  u16*   EXh  = (u16*)q_out;                   //   8 MB (after STATS consumed)
  u16*   EXl  = EXh + (size_t)NROWS * DD;      //   8 MB

  k_split_wT<<<dim3(64, 16), 256, 0, stream>>>(W1, W1ht, W1lt, INCH, CH);
  k_split_wT<<<dim3(8, 64), 256, 0, stream>>>(W2, W2ht, W2lt, CH, DD);
  k_prep_le<<<256, 256, 0, stream>>>(emb, LEh, LEm, LEl);

  k_gemm1<<<dim3(8, 64), 512, 0, stream>>>(x, W1ht, W1lt, Hh, Hl, STATS);
  k_rowstats<<<NROWS / 256, 256, 0, stream>>>(STATS, MU2);
  k_gemm2<<<NROWS / 64, 512, 0, stream>>>(Hh, Hl, W2ht, W2lt, ln_g, ln_b, MU2, b2,
                                          z_out, EXh, EXl, SELF);

  k_dots<<<dim3(8, 128), 256, 0, stream>>>(EXh, EXl, LEh, LEm, LEl, PV, PI);
  k_scan<<<4096, 256, 0, stream>>>(PV, PI, SELF, emb, q_out, KL);
  k_loss<<<1, 256, 0, stream>>>(KL, masks, loss_out);
}